// Round 1
// baseline (1160.565 us; speedup 1.0000x reference)
//
#include <hip/hip_runtime.h>
#include <math.h>

#define Bsz 16
#define Cch 256
#define Lsq 2048
#define Emb 512
#define Nst 64
#define Hch 512   // 2C

typedef _Float16 f16;
typedef _Float16 f16x8 __attribute__((ext_vector_type(8)));
typedef _Float16 f16x4 __attribute__((ext_vector_type(4)));
typedef float f32x4 __attribute__((ext_vector_type(4)));

__device__ __forceinline__ float sigmoidf_(float x) { return 1.0f/(1.0f + __expf(-x)); }
__device__ __forceinline__ float gelu_tanh(float y) {
  float z = 0.7978845608028654f*(y + 0.044715f*y*y*y);
  return 0.5f*y*(1.0f + tanhf(z));
}

// ---------------- small prep kernels ----------------

// d[b,c] = emb[b,:] . dp_W[c,:] + dp_b[c]
__global__ void k_emb(const float* __restrict__ emb, const float* __restrict__ dpW,
                      const float* __restrict__ dpb, float* __restrict__ d) {
  int b = blockIdx.x, c = threadIdx.x;
  const float* e = emb + b*Emb;
  const float* w = dpW + c*Emb;
  float s = dpb[c];
  for (int k = 0; k < Emb; ++k) s += e[k]*w[k];
  d[b*Cch + c] = s;
}

__global__ void k_f2h(const float* __restrict__ src, f16* __restrict__ dst, int n) {
  int i = blockIdx.x*256 + threadIdx.x;
  if (i < n) dst[i] = (f16)src[i];
}

// xd[b,c,l] = fp16(x + d[b,c])   (vectorized by 4 along l)
__global__ void k_addemb(const float* __restrict__ x, const float* __restrict__ d,
                         f16* __restrict__ xd) {
  int i = blockIdx.x*256 + threadIdx.x;          // over B*C*L/4
  const float4* x4 = (const float4*)x;
  float4 v = x4[i];
  int bc = (i*4)/Lsq;
  float dd = d[bc];
  f16x4 o;
  o[0] = (f16)(v.x+dd); o[1] = (f16)(v.y+dd); o[2] = (f16)(v.z+dd); o[3] = (f16)(v.w+dd);
  ((f16x4*)xd)[i] = o;
}

// Per (h,n): w = exp(dt*A), cc = 2*Ct (re / -im) with Ct = C*(w-1)/A
__global__ void k_s4prep(const float* __restrict__ log_dt,
                         const float* __restrict__ A_re, const float* __restrict__ A_im,
                         const float* __restrict__ C_re, const float* __restrict__ C_im,
                         float* __restrict__ w_re, float* __restrict__ w_im,
                         float* __restrict__ ccr, float* __restrict__ cci) {
  int i = blockIdx.x*256 + threadIdx.x;
  if (i >= Hch*Nst) return;
  int h = i >> 6;
  float dt = expf(log_dt[h]);
  float Ar = A_re[i], Ai = A_im[i];
  float er = expf(dt*Ar);
  float wr = er*cosf(dt*Ai), wi = er*sinf(dt*Ai);
  float mag = Ar*Ar + Ai*Ai;
  float nr = wr - 1.0f, ni = wi;
  float qr = (nr*Ar + ni*Ai)/mag, qi = (ni*Ar - nr*Ai)/mag;
  float cr = C_re[i], ci = C_im[i];
  float tr = cr*qr - ci*qi, ti = cr*qi + ci*qr;
  w_re[i] = wr; w_im[i] = wi; ccr[i] = 2.0f*tr; cci[i] = -2.0f*ti;
}

// ---------------- S4 diagonal recurrence + D-skip + GELU ----------------
// one wave per (b,h); lane = state n; chunk = 32 timesteps; LDS transpose reduce
__global__ __launch_bounds__(256) void k_s4rec(
    const float* __restrict__ u, const float* __restrict__ w_re_,
    const float* __restrict__ w_im_, const float* __restrict__ ccr_,
    const float* __restrict__ cci_, const float* __restrict__ Dvec,
    f16* __restrict__ g) {
  __shared__ __align__(16) float lds[4][32][68];
  int wv = threadIdx.x >> 6;
  int lane = threadIdx.x & 63;
  int wid = blockIdx.x*4 + wv;
  int b = wid >> 9;
  int h = wid & 511;
  float wr = w_re_[h*Nst + lane];
  float wi = w_im_[h*Nst + lane];
  float cr = ccr_[h*Nst + lane];
  float ci = cci_[h*Nst + lane];
  float Dh = Dvec[h];
  const float* ub = u + ((size_t)b*Hch + h)*Lsq;
  f16* gb = g + ((size_t)b*Hch + h)*Lsq;
  float sre = 0.f, sim = 0.f;
  int r = lane & 31, hh = lane >> 5;
  for (int l0 = 0; l0 < Lsq; l0 += 32) {
    float uv = ub[l0 + r];
    #pragma unroll
    for (int j = 0; j < 32; ++j) {
      float ubc = __shfl(uv, j);
      float nre = fmaf(wr, sre, fmaf(-wi, sim, ubc));
      float nim = fmaf(wr, sim, wi*sre);
      sre = nre; sim = nim;
      lds[wv][j][lane] = fmaf(cr, sre, ci*sim);
    }
    __syncthreads();
    float4 a4 = {0,0,0,0};
    const float4* rowp = (const float4*)&lds[wv][r][hh*32];
    #pragma unroll
    for (int t = 0; t < 8; ++t) {
      float4 v = rowp[t];
      a4.x += v.x; a4.y += v.y; a4.z += v.z; a4.w += v.w;
    }
    float tot = (a4.x+a4.y) + (a4.z+a4.w);
    tot += __shfl_xor(tot, 32);
    if (hh == 0) {
      float y = tot + Dh*uv;
      gb[l0 + r] = (f16)gelu_tanh(y);
    }
    __syncthreads();
  }
}

// ---------------- MFMA fp16 GEMM, BM=BN=128, BK=32, 4 waves ----------------
// MODE 0: out fp32 = W@act + bias              (in-projection)
// MODE 1: out fp16 = (Wa@act+ba)*sigmoid(Wb@act+bb)   (oW + GLU, Wb = rows 512..1023)
// MODE 2: out fp32: rows<256 -> (x + v)/sqrt2 ; rows>=256 -> skip  (out-projection)
template<int KD, int MODE>
__global__ __launch_bounds__(256) void k_gemm(
    const f16* __restrict__ W, const f16* __restrict__ Bact,
    const float* __restrict__ bias, const float* __restrict__ xres,
    float* __restrict__ outF, f16* __restrict__ outH) {
  constexpr int NT = (MODE == 1) ? 2 : 1;
  __shared__ __align__(16) f16 As[NT][128][40];
  __shared__ uint32_t Bs[16*133];
  int tid = threadIdx.x;
  int wv = tid >> 6, lane = tid & 63;
  int nt = blockIdx.x;            // 0..255
  int mt = blockIdx.y;            // 0..3
  int bb = nt >> 4;
  int l0 = (nt & 15)*128;
  int m0 = mt*128;
  int wm = (wv & 1)*64, wn = (wv >> 1)*64;
  int qd = lane >> 4, ln16 = lane & 15;

  f32x4 acc[NT][4][4];
  #pragma unroll
  for (int t = 0; t < NT; ++t)
    for (int i = 0; i < 4; ++i)
      for (int j = 0; j < 4; ++j)
        acc[t][i][j] = (f32x4){0.f,0.f,0.f,0.f};

  const f16* Bbase = Bact + (size_t)bb*KD*Lsq + l0;
  int kp = tid & 15, nch = tid >> 4;

  for (int kk = 0; kk < KD; kk += 32) {
    // stage A tile(s): rows m0..m0+127 (+512 for second tile), k kk..kk+31
    #pragma unroll
    for (int c = 0; c < 2*NT; ++c) {
      int c2 = tid + 256*(c & 1);
      int row = c2 >> 2;
      int kc = (c2 & 3)*8;
      int tsel = c >> 1;
      const f16* src = W + (size_t)(m0 + row + tsel*512)*KD + kk + kc;
      *(f16x8*)&As[tsel][row][kc] = *(const f16x8*)src;
    }
    // stage B: pair-pack rows (kk+2kp, kk+2kp+1), n = nch*8..+7
    {
      const f16* b0 = Bbase + (size_t)(kk + 2*kp)*Lsq + nch*8;
      f16x8 r0 = *(const f16x8*)b0;
      f16x8 r1 = *(const f16x8*)(b0 + Lsq);
      #pragma unroll
      for (int e = 0; e < 8; ++e) {
        union { f16 h[2]; uint32_t w; } pk;
        pk.h[0] = r0[e]; pk.h[1] = r1[e];
        Bs[kp*133 + nch*8 + e] = pk.w;
      }
    }
    __syncthreads();
    f16x8 afr[NT][4];
    #pragma unroll
    for (int i = 0; i < 4; ++i)
      for (int t = 0; t < NT; ++t)
        afr[t][i] = *(const f16x8*)&As[t][wm + i*16 + ln16][qd*8];
    #pragma unroll
    for (int j = 0; j < 4; ++j) {
      int n = wn + j*16 + ln16;
      union { uint32_t w2[4]; f16x8 v; } bu;
      #pragma unroll
      for (int r2 = 0; r2 < 4; ++r2) bu.w2[r2] = Bs[(qd*4 + r2)*133 + n];
      #pragma unroll
      for (int i = 0; i < 4; ++i)
        for (int t = 0; t < NT; ++t)
          acc[t][i][j] = __builtin_amdgcn_mfma_f32_16x16x32_f16(afr[t][i], bu.v, acc[t][i][j], 0, 0, 0);
    }
    __syncthreads();
  }

  #pragma unroll
  for (int i = 0; i < 4; ++i)
    for (int j = 0; j < 4; ++j)
      for (int r = 0; r < 4; ++r) {
        int ml = wm + i*16 + qd*4 + r;
        int nl = wn + j*16 + ln16;
        int mg = m0 + ml;
        int l  = l0 + nl;
        if (MODE == 0) {
          outF[((size_t)bb*Hch + mg)*Lsq + l] = acc[0][i][j][r] + bias[mg];
        } else if (MODE == 1) {
          float va = acc[0][i][j][r] + bias[mg];
          float vb = acc[1][i][j][r] + bias[512 + mg];
          outH[((size_t)bb*Hch + mg)*Lsq + l] = (f16)(va * sigmoidf_(vb));
        } else {
          float v = acc[0][i][j][r] + bias[mg];
          if (mg < Cch) {
            size_t idx = ((size_t)bb*Cch + mg)*Lsq + l;
            outF[idx] = (v + xres[idx]) * 0.7071067811865476f;
          } else {
            size_t idx = ((size_t)bb*Cch + (mg - Cch))*Lsq + l;
            outF[(size_t)Bsz*Cch*Lsq + idx] = v;
          }
        }
      }
}

// ---------------- LayerNorm over channels (fp16 in) ----------------
// block: 256 thr = 4 waves; 64 l-positions; wave wv reduces h in [wv*128, wv*128+128)
// MODE 0: fp32 out (LN only).  MODE 1: fused gate: t = sigmoid(yn[c])*tanh(yn[c+256]), fp16 out [B,C,L]
template<int MODE>
__global__ __launch_bounds__(256) void k_ln(const f16* __restrict__ v,
                                            const float* __restrict__ gam, const float* __restrict__ bet,
                                            float* __restrict__ outF, f16* __restrict__ outH) {
  __shared__ float red[2][4][64];
  int b = blockIdx.x >> 5;
  int l = (blockIdx.x & 31)*64 + (threadIdx.x & 63);
  int wv = threadIdx.x >> 6, lane = threadIdx.x & 63;
  const f16* base = v + (size_t)b*Hch*Lsq + l;
  float s = 0.f, s2 = 0.f;
  for (int h = wv*128; h < wv*128 + 128; ++h) {
    float xv = (float)base[(size_t)h*Lsq];
    s += xv; s2 += xv*xv;
  }
  red[0][wv][lane] = s; red[1][wv][lane] = s2;
  __syncthreads();
  s  = red[0][0][lane] + red[0][1][lane] + red[0][2][lane] + red[0][3][lane];
  s2 = red[1][0][lane] + red[1][1][lane] + red[1][2][lane] + red[1][3][lane];
  float mu = s*(1.0f/Hch);
  float var = s2*(1.0f/Hch) - mu*mu;
  float rs = rsqrtf(var + 1e-5f);
  if (MODE == 0) {
    float* ob = outF + (size_t)b*Hch*Lsq + l;
    for (int h = wv*128; h < wv*128 + 128; ++h)
      ob[(size_t)h*Lsq] = ((float)base[(size_t)h*Lsq] - mu)*rs*gam[h] + bet[h];
  } else {
    f16* ob = outH + (size_t)b*Cch*Lsq + l;
    for (int c = wv*64; c < wv*64 + 64; ++c) {
      float xg = ((float)base[(size_t)c*Lsq] - mu)*rs*gam[c] + bet[c];
      float xf = ((float)base[(size_t)(c+Cch)*Lsq] - mu)*rs*gam[c+Cch] + bet[c+Cch];
      float xfc = fminf(fmaxf(xf, -15.f), 15.f);
      float e = __expf(2.f*xfc);
      ob[(size_t)c*Lsq] = (f16)(sigmoidf_(xg) * ((e-1.f)/(e+1.f)));
    }
  }
}

// ---------------- launch ----------------
extern "C" void kernel_launch(void* const* d_in, const int* in_sizes, int n_in,
                              void* d_out, int out_size, void* d_ws, size_t ws_size,
                              hipStream_t stream) {
  const float* x    = (const float*)d_in[0];
  const float* emb  = (const float*)d_in[1];
  const float* dpW  = (const float*)d_in[2];
  const float* dpb  = (const float*)d_in[3];
  const float* inW  = (const float*)d_in[4];
  const float* inb  = (const float*)d_in[5];
  const float* outW = (const float*)d_in[6];
  const float* outb = (const float*)d_in[7];
  const float* ln1g = (const float*)d_in[8];
  const float* ln1b = (const float*)d_in[9];
  const float* ln2g = (const float*)d_in[10];
  const float* ln2b = (const float*)d_in[11];
  const float* s4[2][8];
  for (int ly = 0; ly < 2; ++ly)
    for (int k = 0; k < 8; ++k) s4[ly][k] = (const float*)d_in[12 + ly*8 + k];
  // s4[ly]: 0 log_dt, 1 A_re, 2 A_im, 3 C_re, 4 C_im, 5 D, 6 oW, 7 ob

  char* p = (char*)d_ws;
  auto alloc = [&](size_t bytes) { char* r = p; p += (bytes + 255) & ~(size_t)255; return r; };
  f16* inW16  = (f16*)alloc((size_t)Hch*Cch*2);
  f16* oW16_0 = (f16*)alloc((size_t)2*Hch*Hch*2);
  f16* oW16_1 = (f16*)alloc((size_t)2*Hch*Hch*2);
  f16* outW16 = (f16*)alloc((size_t)2*Cch*Cch*2);
  float* dbuf = (float*)alloc((size_t)Bsz*Cch*4);
  float* prm[2][4];
  for (int ly = 0; ly < 2; ++ly)
    for (int k = 0; k < 4; ++k) prm[ly][k] = (float*)alloc((size_t)Hch*Nst*4);
  f16*  xd   = (f16*)alloc((size_t)Bsz*Cch*Lsq*2);   // also reused as t-buffer
  float* ub  = (float*)alloc((size_t)Bsz*Hch*Lsq*4);
  f16*  gbuf = (f16*)alloc((size_t)Bsz*Hch*Lsq*2);
  f16*  glu  = (f16*)alloc((size_t)Bsz*Hch*Lsq*2);
  f16*  oW16[2] = {oW16_0, oW16_1};

  // prep
  k_emb<<<Bsz, Cch, 0, stream>>>(emb, dpW, dpb, dbuf);
  k_f2h<<<(Hch*Cch+255)/256, 256, 0, stream>>>(inW, inW16, Hch*Cch);
  k_f2h<<<(2*Hch*Hch+255)/256, 256, 0, stream>>>(s4[0][6], oW16_0, 2*Hch*Hch);
  k_f2h<<<(2*Hch*Hch+255)/256, 256, 0, stream>>>(s4[1][6], oW16_1, 2*Hch*Hch);
  k_f2h<<<(2*Cch*Cch+255)/256, 256, 0, stream>>>(outW, outW16, 2*Cch*Cch);
  for (int ly = 0; ly < 2; ++ly)
    k_s4prep<<<(Hch*Nst+255)/256, 256, 0, stream>>>(s4[ly][0], s4[ly][1], s4[ly][2],
        s4[ly][3], s4[ly][4], prm[ly][0], prm[ly][1], prm[ly][2], prm[ly][3]);
  k_addemb<<<(Bsz*Cch*Lsq/4)/256, 256, 0, stream>>>(x, dbuf, xd);

  dim3 gg(256, 4), bl(256);
  // in-projection
  k_gemm<Cch, 0><<<gg, bl, 0, stream>>>(inW16, xd, inb, nullptr, ub, nullptr);
  // S4 layer 1
  k_s4rec<<<Bsz*Hch/4, 256, 0, stream>>>(ub, prm[0][0], prm[0][1], prm[0][2], prm[0][3], s4[0][5], gbuf);
  k_gemm<Hch, 1><<<gg, bl, 0, stream>>>(oW16[0], gbuf, s4[0][7], nullptr, nullptr, glu);
  k_ln<0><<<Bsz*32, 256, 0, stream>>>(glu, ln1g, ln1b, ub, nullptr);
  // S4 layer 2
  k_s4rec<<<Bsz*Hch/4, 256, 0, stream>>>(ub, prm[1][0], prm[1][1], prm[1][2], prm[1][3], s4[1][5], gbuf);
  k_gemm<Hch, 1><<<gg, bl, 0, stream>>>(oW16[1], gbuf, s4[1][7], nullptr, nullptr, glu);
  k_ln<1><<<Bsz*32, 256, 0, stream>>>(glu, ln2g, ln2b, nullptr, xd);
  // out-projection (+ residual/skip split)
  k_gemm<Cch, 2><<<gg, bl, 0, stream>>>(outW16, xd, outb, x, (float*)d_out, nullptr);
}

// Round 2
// 774.732 us; speedup vs baseline: 1.4980x; 1.4980x over previous
//
#include <hip/hip_runtime.h>
#include <math.h>

#define Bsz 16
#define Cch 256
#define Lsq 2048
#define Emb 512
#define Nst 64
#define Hch 512   // 2C
#define KGP 2240  // padded reversed-kernel pitch per h

typedef _Float16 f16;
typedef _Float16 f16x8 __attribute__((ext_vector_type(8)));
typedef _Float16 f16x4 __attribute__((ext_vector_type(4)));
typedef float f32x4 __attribute__((ext_vector_type(4)));

__device__ __forceinline__ float sigmoidf_(float x) { return 1.0f/(1.0f + __expf(-x)); }
__device__ __forceinline__ float gelu_tanh(float y) {
  float z = 0.7978845608028654f*(y + 0.044715f*y*y*y);
  return 0.5f*y*(1.0f + tanhf(z));
}

// ---------------- small prep kernels ----------------

__global__ void k_emb(const float* __restrict__ emb, const float* __restrict__ dpW,
                      const float* __restrict__ dpb, float* __restrict__ d) {
  int b = blockIdx.x, c = threadIdx.x;
  const float* e = emb + b*Emb;
  const float* w = dpW + c*Emb;
  float s = dpb[c];
  for (int k = 0; k < Emb; ++k) s += e[k]*w[k];
  d[b*Cch + c] = s;
}

__global__ void k_f2h(const float* __restrict__ src, f16* __restrict__ dst, int n) {
  int i = blockIdx.x*256 + threadIdx.x;
  if (i < n) dst[i] = (f16)src[i];
}

__global__ void k_addemb(const float* __restrict__ x, const float* __restrict__ d,
                         f16* __restrict__ xd) {
  int i = blockIdx.x*256 + threadIdx.x;          // over B*C*L/4
  const float4* x4 = (const float4*)x;
  float4 v = x4[i];
  int bc = (i*4)/Lsq;
  float dd = d[bc];
  f16x4 o;
  o[0] = (f16)(v.x+dd); o[1] = (f16)(v.y+dd); o[2] = (f16)(v.z+dd); o[3] = (f16)(v.w+dd);
  ((f16x4*)xd)[i] = o;
}

// Per (h,n): w = exp(dt*A), cc = 2*Ct (re / -im) with Ct = C*(w-1)/A
__global__ void k_s4prep(const float* __restrict__ log_dt,
                         const float* __restrict__ A_re, const float* __restrict__ A_im,
                         const float* __restrict__ C_re, const float* __restrict__ C_im,
                         float* __restrict__ w_re, float* __restrict__ w_im,
                         float* __restrict__ ccr, float* __restrict__ cci) {
  int i = blockIdx.x*256 + threadIdx.x;
  if (i >= Hch*Nst) return;
  int h = i >> 6;
  float dt = expf(log_dt[h]);
  float Ar = A_re[i], Ai = A_im[i];
  float er = expf(dt*Ar);
  float wr = er*cosf(dt*Ai), wi = er*sinf(dt*Ai);
  float mag = Ar*Ar + Ai*Ai;
  float nr = wr - 1.0f, ni = wi;
  float qr = (nr*Ar + ni*Ai)/mag, qi = (ni*Ar - nr*Ai)/mag;
  float cr = C_re[i], ci = C_im[i];
  float tr = cr*qr - ci*qi, ti = cr*qi + ci*qr;
  w_re[i] = wr; w_im[i] = wi; ccr[i] = 2.0f*tr; cci[i] = -2.0f*ti;
}

// ---------------- kernel generation: K[h,l] = sum_n ccr*Re(w^l)+cci*Im(w^l), K[0]+=D ----
// writes reversed kernel, two parity copies, zero-padded to KGP
__global__ __launch_bounds__(256) void k_kgen(
    const float* __restrict__ w_re, const float* __restrict__ w_im,
    const float* __restrict__ ccr, const float* __restrict__ cci,
    const float* __restrict__ Dvec,
    f16* __restrict__ Ke, f16* __restrict__ Ko) {
  __shared__ float2 wbt[64][66];   // [j = l&63][n], padded pitch
  __shared__ float2 wat[32][64];   // [a = l>>6][n]
  __shared__ float Kf[2048];
  __shared__ float2 ccs[64];
  int h = blockIdx.x, tid = threadIdx.x;
  if (tid < 64) {
    int n = tid;
    double wr = (double)w_re[h*64+n], wi = (double)w_im[h*64+n];
    double br = 1.0, bi = 0.0;
    for (int j = 0; j < 64; ++j) {
      wbt[j][n] = make_float2((float)br, (float)bi);
      double t = br*wr - bi*wi; bi = br*wi + bi*wr; br = t;
    }
    double ar = 1.0, ai = 0.0;   // (br,bi) = w^64 now
    for (int a = 0; a < 32; ++a) {
      wat[a][n] = make_float2((float)ar, (float)ai);
      double t = ar*br - ai*bi; ai = ar*bi + ai*br; ar = t;
    }
    ccs[n] = make_float2(ccr[h*64+n], cci[h*64+n]);
  }
  __syncthreads();
  int lane = tid & 63;
  #pragma unroll
  for (int li = 0; li < 8; ++li) {
    int l = li*256 + tid;
    int a = l >> 6;              // wave-uniform
    float acc = 0.f;
    for (int n = 0; n < 64; n += 2) {
      float4 wb = *(const float4*)&wbt[lane][n];
      float4 wa = *(const float4*)&wat[a][n];
      float4 cc = *(const float4*)&ccs[n];
      float wr0 = wa.x*wb.x - wa.y*wb.y, wi0 = wa.x*wb.y + wa.y*wb.x;
      float wr1 = wa.z*wb.z - wa.w*wb.w, wi1 = wa.z*wb.w + wa.w*wb.z;
      acc += cc.x*wr0 + cc.y*wi0 + cc.z*wr1 + cc.w*wi1;
    }
    if (l == 0) acc += Dvec[h];
    Kf[l] = acc;
  }
  __syncthreads();
  f16* keh = Ke + (size_t)h*KGP;
  f16* koh = Ko + (size_t)h*KGP;
  for (int q = tid; q < KGP; q += 256) {
    float e = (q < 2048) ? Kf[2047 - q] : 0.f;   // KR[q] = K[2047-q]
    float o = (q < 2047) ? Kf[2046 - q] : 0.f;   // KRo[q] = KR[q+1]
    keh[q] = (f16)e; koh[q] = (f16)o;
  }
}

// ---------------- S4 causal conv as Toeplitz MFMA + GELU ----------------
// one block per h; U[16 b][2048 l] fp16 in LDS (XOR-swizzled granules);
// A-frags from L2 (even/odd reversed-kernel copies) via register sliding window.
__device__ __forceinline__ f16x8 ldfrag(const f16* __restrict__ ke,
                                        const f16* __restrict__ ko, int q) {
  const f16* p = (q & 1) ? (ko + (q - 1)) : (ke + q);   // 4B-aligned either way
  union { uint32_t u[4]; f16x8 v; } r;
  const uint32_t* pu = (const uint32_t*)p;
  r.u[0] = pu[0]; r.u[1] = pu[1]; r.u[2] = pu[2]; r.u[3] = pu[3];
  return r.v;
}

__global__ __launch_bounds__(256) void k_conv(
    const f16* __restrict__ u, const f16* __restrict__ Ke, const f16* __restrict__ Ko,
    f16* __restrict__ g) {
  __shared__ __align__(16) f16 Ul[16*2048];   // exactly 64 KB
  int h = blockIdx.x, tid = threadIdx.x;
  {
    int b = tid >> 4, pr = tid & 15;
    const f16* src = u + ((size_t)b*Hch + h)*Lsq;
    f16* dst = &Ul[b*2048];
    #pragma unroll
    for (int c = 0; c < 16; ++c) {
      int gs = c*16 + pr;                       // granule (8 f16)
      *(f16x8*)&dst[(gs ^ b)*8] = *(const f16x8*)(src + gs*8);
    }
  }
  __syncthreads();
  int wv = tid >> 6, lane = tid & 63;
  int m = lane & 15, qd = lane >> 4;            // m: A-row / B-col(b) / D-col
  const f16* keh = Ke + (size_t)h*KGP;
  const f16* koh = Ko + (size_t)h*KGP;
  f16* gb = g + ((size_t)m*Hch + h)*Lsq;        // output batch = m
  const f16* ulb = &Ul[m*2048];
  for (int pass = 0; pass < 4; ++pass) {
    int P = pass*4 + ((wv + pass) & 3);         // balanced panel rotation
    int i0 = P*128;
    int qb0 = 2047 - i0 - m + qd*8;             // frag q: qb0 - 16t + 32s (+e)
    f32x4 acc[8];
    #pragma unroll
    for (int t = 0; t < 8; ++t) acc[t] = (f32x4){0.f,0.f,0.f,0.f};
    f16x8 W[8];
    #pragma unroll
    for (int t = 0; t < 8; ++t) W[t] = ldfrag(keh, koh, qb0 - 16*t);
    int steps = 4*(P+1);
    for (int s4i = 0; s4i < steps; s4i += 4) {
      #pragma unroll
      for (int ph = 0; ph < 4; ++ph) {
        int s = s4i + ph;
        f16x8 bf = *(const f16x8*)&ulb[((4*s + qd) ^ m)*8];
        // prefetch next step's two fresh frags (padded region keeps OOB safe)
        f16x8 nf0 = ldfrag(keh, koh, qb0 + 32*(s+1));
        f16x8 nf1 = ldfrag(keh, koh, qb0 - 16 + 32*(s+1));
        #pragma unroll
        for (int t = 0; t < 8; ++t)
          acc[t] = __builtin_amdgcn_mfma_f32_16x16x32_f16(W[(t - 2*ph) & 7], bf, acc[t], 0, 0, 0);
        W[(6 - 2*ph) & 7] = nf0;   // tile 0 of step s+1
        W[(7 - 2*ph) & 7] = nf1;   // tile 1 of step s+1
      }
    }
    #pragma unroll
    for (int t = 0; t < 8; ++t) {
      f16x4 o;
      #pragma unroll
      for (int r = 0; r < 4; ++r) o[r] = (f16)gelu_tanh(acc[t][r]);
      *(f16x4*)&gb[i0 + 16*t + qd*4] = o;
    }
  }
}

// ---------------- MFMA fp16 GEMM, BM=BN=128, BK=32, 4 waves ----------------
// MODE 0: out fp16 = W@act + bias              (in-projection)
// MODE 1: out fp16 = (Wa@act+ba)*sigmoid(Wb@act+bb)   (oW + GLU, Wb = rows 512..1023)
// MODE 2: out fp32: rows<256 -> (x + v)/sqrt2 ; rows>=256 -> skip  (out-projection)
template<int KD, int MODE>
__global__ __launch_bounds__(256) void k_gemm(
    const f16* __restrict__ W, const f16* __restrict__ Bact,
    const float* __restrict__ bias, const float* __restrict__ xres,
    float* __restrict__ outF, f16* __restrict__ outH) {
  constexpr int NT = (MODE == 1) ? 2 : 1;
  __shared__ __align__(16) f16 As[NT][128][40];
  __shared__ uint32_t Bs[16*133];
  int tid = threadIdx.x;
  int wv = tid >> 6, lane = tid & 63;
  int nt = blockIdx.x;            // 0..255
  int mt = blockIdx.y;            // 0..3
  int bb = nt >> 4;
  int l0 = (nt & 15)*128;
  int m0 = mt*128;
  int wm = (wv & 1)*64, wn = (wv >> 1)*64;
  int qd = lane >> 4, ln16 = lane & 15;

  f32x4 acc[NT][4][4];
  #pragma unroll
  for (int t = 0; t < NT; ++t)
    for (int i = 0; i < 4; ++i)
      for (int j = 0; j < 4; ++j)
        acc[t][i][j] = (f32x4){0.f,0.f,0.f,0.f};

  const f16* Bbase = Bact + (size_t)bb*KD*Lsq + l0;
  int kp = tid & 15, nch = tid >> 4;

  for (int kk = 0; kk < KD; kk += 32) {
    #pragma unroll
    for (int c = 0; c < 2*NT; ++c) {
      int c2 = tid + 256*(c & 1);
      int row = c2 >> 2;
      int kc = (c2 & 3)*8;
      int tsel = c >> 1;
      const f16* src = W + (size_t)(m0 + row + tsel*512)*KD + kk + kc;
      *(f16x8*)&As[tsel][row][kc] = *(const f16x8*)src;
    }
    {
      const f16* b0 = Bbase + (size_t)(kk + 2*kp)*Lsq + nch*8;
      f16x8 r0 = *(const f16x8*)b0;
      f16x8 r1 = *(const f16x8*)(b0 + Lsq);
      #pragma unroll
      for (int e = 0; e < 8; ++e) {
        union { f16 h[2]; uint32_t w; } pk;
        pk.h[0] = r0[e]; pk.h[1] = r1[e];
        Bs[kp*133 + nch*8 + e] = pk.w;
      }
    }
    __syncthreads();
    f16x8 afr[NT][4];
    #pragma unroll
    for (int i = 0; i < 4; ++i)
      for (int t = 0; t < NT; ++t)
        afr[t][i] = *(const f16x8*)&As[t][wm + i*16 + ln16][qd*8];
    #pragma unroll
    for (int j = 0; j < 4; ++j) {
      int n = wn + j*16 + ln16;
      union { uint32_t w2[4]; f16x8 v; } bu;
      #pragma unroll
      for (int r2 = 0; r2 < 4; ++r2) bu.w2[r2] = Bs[(qd*4 + r2)*133 + n];
      #pragma unroll
      for (int i = 0; i < 4; ++i)
        for (int t = 0; t < NT; ++t)
          acc[t][i][j] = __builtin_amdgcn_mfma_f32_16x16x32_f16(afr[t][i], bu.v, acc[t][i][j], 0, 0, 0);
    }
    __syncthreads();
  }

  #pragma unroll
  for (int i = 0; i < 4; ++i)
    for (int j = 0; j < 4; ++j)
      for (int r = 0; r < 4; ++r) {
        int ml = wm + i*16 + qd*4 + r;
        int nl = wn + j*16 + ln16;
        int mg = m0 + ml;
        int l  = l0 + nl;
        if (MODE == 0) {
          outH[((size_t)bb*Hch + mg)*Lsq + l] = (f16)(acc[0][i][j][r] + bias[mg]);
        } else if (MODE == 1) {
          float va = acc[0][i][j][r] + bias[mg];
          float vb = acc[1][i][j][r] + bias[512 + mg];
          outH[((size_t)bb*Hch + mg)*Lsq + l] = (f16)(va * sigmoidf_(vb));
        } else {
          float v = acc[0][i][j][r] + bias[mg];
          if (mg < Cch) {
            size_t idx = ((size_t)bb*Cch + mg)*Lsq + l;
            outF[idx] = (v + xres[idx]) * 0.7071067811865476f;
          } else {
            size_t idx = ((size_t)bb*Cch + (mg - Cch))*Lsq + l;
            outF[(size_t)Bsz*Cch*Lsq + idx] = v;
          }
        }
      }
}

// ---------------- LayerNorm over channels (fp16 in) ----------------
// MODE 0: fp16 out (LN only).  MODE 1: fused gate: sigmoid(yn[c])*tanh(yn[c+256]), fp16 out
template<int MODE>
__global__ __launch_bounds__(256) void k_ln(const f16* __restrict__ v,
                                            const float* __restrict__ gam, const float* __restrict__ bet,
                                            float* __restrict__ outF, f16* __restrict__ outH) {
  __shared__ float red[2][4][64];
  int b = blockIdx.x >> 5;
  int l = (blockIdx.x & 31)*64 + (threadIdx.x & 63);
  int wv = threadIdx.x >> 6, lane = threadIdx.x & 63;
  const f16* base = v + (size_t)b*Hch*Lsq + l;
  float s = 0.f, s2 = 0.f;
  for (int h = wv*128; h < wv*128 + 128; ++h) {
    float xv = (float)base[(size_t)h*Lsq];
    s += xv; s2 += xv*xv;
  }
  red[0][wv][lane] = s; red[1][wv][lane] = s2;
  __syncthreads();
  s  = red[0][0][lane] + red[0][1][lane] + red[0][2][lane] + red[0][3][lane];
  s2 = red[1][0][lane] + red[1][1][lane] + red[1][2][lane] + red[1][3][lane];
  float mu = s*(1.0f/Hch);
  float var = s2*(1.0f/Hch) - mu*mu;
  float rs = rsqrtf(var + 1e-5f);
  if (MODE == 0) {
    f16* ob = outH + (size_t)b*Hch*Lsq + l;
    for (int h = wv*128; h < wv*128 + 128; ++h)
      ob[(size_t)h*Lsq] = (f16)(((float)base[(size_t)h*Lsq] - mu)*rs*gam[h] + bet[h]);
  } else {
    f16* ob = outH + (size_t)b*Cch*Lsq + l;
    for (int c = wv*64; c < wv*64 + 64; ++c) {
      float xg = ((float)base[(size_t)c*Lsq] - mu)*rs*gam[c] + bet[c];
      float xf = ((float)base[(size_t)(c+Cch)*Lsq] - mu)*rs*gam[c+Cch] + bet[c+Cch];
      float xfc = fminf(fmaxf(xf, -15.f), 15.f);
      float e = __expf(2.f*xfc);
      ob[(size_t)c*Lsq] = (f16)(sigmoidf_(xg) * ((e-1.f)/(e+1.f)));
    }
  }
}

// ---------------- launch ----------------
extern "C" void kernel_launch(void* const* d_in, const int* in_sizes, int n_in,
                              void* d_out, int out_size, void* d_ws, size_t ws_size,
                              hipStream_t stream) {
  const float* x    = (const float*)d_in[0];
  const float* emb  = (const float*)d_in[1];
  const float* dpW  = (const float*)d_in[2];
  const float* dpb  = (const float*)d_in[3];
  const float* inW  = (const float*)d_in[4];
  const float* inb  = (const float*)d_in[5];
  const float* outW = (const float*)d_in[6];
  const float* outb = (const float*)d_in[7];
  const float* ln1g = (const float*)d_in[8];
  const float* ln1b = (const float*)d_in[9];
  const float* ln2g = (const float*)d_in[10];
  const float* ln2b = (const float*)d_in[11];
  const float* s4[2][8];
  for (int ly = 0; ly < 2; ++ly)
    for (int k = 0; k < 8; ++k) s4[ly][k] = (const float*)d_in[12 + ly*8 + k];
  // s4[ly]: 0 log_dt, 1 A_re, 2 A_im, 3 C_re, 4 C_im, 5 D, 6 oW, 7 ob

  char* p = (char*)d_ws;
  auto alloc = [&](size_t bytes) { char* r = p; p += (bytes + 255) & ~(size_t)255; return r; };
  f16* inW16  = (f16*)alloc((size_t)Hch*Cch*2);
  f16* oW16_0 = (f16*)alloc((size_t)2*Hch*Hch*2);
  f16* oW16_1 = (f16*)alloc((size_t)2*Hch*Hch*2);
  f16* outW16 = (f16*)alloc((size_t)2*Cch*Cch*2);
  float* dbuf = (float*)alloc((size_t)Bsz*Cch*4);
  float* prm[2][4];
  for (int ly = 0; ly < 2; ++ly)
    for (int k = 0; k < 4; ++k) prm[ly][k] = (float*)alloc((size_t)Hch*Nst*4);
  f16* kge[2], *kgo[2];
  for (int ly = 0; ly < 2; ++ly) {
    kge[ly] = (f16*)alloc((size_t)Hch*KGP*2);
    kgo[ly] = (f16*)alloc((size_t)Hch*KGP*2);
  }
  f16*  xd   = (f16*)alloc((size_t)Bsz*Cch*Lsq*2);
  f16*  u16g = (f16*)alloc((size_t)Bsz*Hch*Lsq*2);
  f16*  gbuf = (f16*)alloc((size_t)Bsz*Hch*Lsq*2);
  f16*  glu  = (f16*)alloc((size_t)Bsz*Hch*Lsq*2);
  f16*  oW16[2] = {oW16_0, oW16_1};

  // prep
  k_emb<<<Bsz, Cch, 0, stream>>>(emb, dpW, dpb, dbuf);
  k_f2h<<<(Hch*Cch+255)/256, 256, 0, stream>>>(inW, inW16, Hch*Cch);
  k_f2h<<<(2*Hch*Hch+255)/256, 256, 0, stream>>>(s4[0][6], oW16_0, 2*Hch*Hch);
  k_f2h<<<(2*Hch*Hch+255)/256, 256, 0, stream>>>(s4[1][6], oW16_1, 2*Hch*Hch);
  k_f2h<<<(2*Cch*Cch+255)/256, 256, 0, stream>>>(outW, outW16, 2*Cch*Cch);
  for (int ly = 0; ly < 2; ++ly) {
    k_s4prep<<<(Hch*Nst+255)/256, 256, 0, stream>>>(s4[ly][0], s4[ly][1], s4[ly][2],
        s4[ly][3], s4[ly][4], prm[ly][0], prm[ly][1], prm[ly][2], prm[ly][3]);
    k_kgen<<<Hch, 256, 0, stream>>>(prm[ly][0], prm[ly][1], prm[ly][2], prm[ly][3],
        s4[ly][5], kge[ly], kgo[ly]);
  }
  k_addemb<<<(Bsz*Cch*Lsq/4)/256, 256, 0, stream>>>(x, dbuf, xd);

  dim3 gg(256, 4), bl(256);
  // in-projection (fp16 out)
  k_gemm<Cch, 0><<<gg, bl, 0, stream>>>(inW16, xd, inb, nullptr, nullptr, u16g);
  // S4 layer 1
  k_conv<<<Hch, 256, 0, stream>>>(u16g, kge[0], kgo[0], gbuf);
  k_gemm<Hch, 1><<<gg, bl, 0, stream>>>(oW16[0], gbuf, s4[0][7], nullptr, nullptr, glu);
  k_ln<0><<<Bsz*32, 256, 0, stream>>>(glu, ln1g, ln1b, nullptr, u16g);
  // S4 layer 2
  k_conv<<<Hch, 256, 0, stream>>>(u16g, kge[1], kgo[1], gbuf);
  k_gemm<Hch, 1><<<gg, bl, 0, stream>>>(oW16[1], gbuf, s4[1][7], nullptr, nullptr, glu);
  k_ln<1><<<Bsz*32, 256, 0, stream>>>(glu, ln2g, ln2b, nullptr, xd);
  // out-projection (+ residual/skip split)
  k_gemm<Cch, 2><<<gg, bl, 0, stream>>>(outW16, xd, outb, x, (float*)d_out, nullptr);
}

// Round 4
// 609.900 us; speedup vs baseline: 1.9029x; 1.2703x over previous
//
#include <hip/hip_runtime.h>
#include <math.h>

#define Bsz 16
#define Cch 256
#define Lsq 2048
#define Emb 512
#define Nst 64
#define Hch 512   // 2C
#define KGP 2240  // padded reversed-kernel pitch per h

typedef _Float16 f16;
typedef _Float16 f16x8 __attribute__((ext_vector_type(8)));
typedef _Float16 f16x4 __attribute__((ext_vector_type(4)));
typedef float f32x4 __attribute__((ext_vector_type(4)));

__device__ __forceinline__ float sigmoidf_(float x) { return 1.0f/(1.0f + __expf(-x)); }
__device__ __forceinline__ float gelu_tanh(float y) {
  float z = 0.7978845608028654f*(y + 0.044715f*y*y*y);
  return 0.5f*y*(1.0f + tanhf(z));
}

// ---------------- small prep kernels ----------------

__global__ void k_emb(const float* __restrict__ emb, const float* __restrict__ dpW,
                      const float* __restrict__ dpb, float* __restrict__ d) {
  int b = blockIdx.x, c = threadIdx.x;
  const float* e = emb + b*Emb;
  const float* w = dpW + c*Emb;
  float s = dpb[c];
  for (int k = 0; k < Emb; ++k) s += e[k]*w[k];
  d[b*Cch + c] = s;
}

__global__ void k_f2h(const float* __restrict__ src, f16* __restrict__ dst, int n) {
  int i = blockIdx.x*256 + threadIdx.x;
  if (i < n) dst[i] = (f16)src[i];
}

__global__ void k_addemb(const float* __restrict__ x, const float* __restrict__ d,
                         f16* __restrict__ xd) {
  int i = blockIdx.x*256 + threadIdx.x;          // over B*C*L/4
  const float4* x4 = (const float4*)x;
  float4 v = x4[i];
  int bc = (i*4)/Lsq;
  float dd = d[bc];
  f16x4 o;
  o[0] = (f16)(v.x+dd); o[1] = (f16)(v.y+dd); o[2] = (f16)(v.z+dd); o[3] = (f16)(v.w+dd);
  ((f16x4*)xd)[i] = o;
}

// Per (h,n): w = exp(dt*A), cc = 2*Ct (re / -im) with Ct = C*(w-1)/A
__global__ void k_s4prep(const float* __restrict__ log_dt,
                         const float* __restrict__ A_re, const float* __restrict__ A_im,
                         const float* __restrict__ C_re, const float* __restrict__ C_im,
                         float* __restrict__ w_re, float* __restrict__ w_im,
                         float* __restrict__ ccr, float* __restrict__ cci) {
  int i = blockIdx.x*256 + threadIdx.x;
  if (i >= Hch*Nst) return;
  int h = i >> 6;
  float dt = expf(log_dt[h]);
  float Ar = A_re[i], Ai = A_im[i];
  float er = expf(dt*Ar);
  float wr = er*cosf(dt*Ai), wi = er*sinf(dt*Ai);
  float mag = Ar*Ar + Ai*Ai;
  float nr = wr - 1.0f, ni = wi;
  float qr = (nr*Ar + ni*Ai)/mag, qi = (ni*Ar - nr*Ai)/mag;
  float cr = C_re[i], ci = C_im[i];
  float tr = cr*qr - ci*qi, ti = cr*qi + ci*qr;
  w_re[i] = wr; w_im[i] = wi; ccr[i] = 2.0f*tr; cci[i] = -2.0f*ti;
}

// ---------------- kernel generation: K[h,l] = sum_n ccr*Re(w^l)+cci*Im(w^l), K[0]+=D ----
// transposed tables: wbt[n][j] (lane=j reads stride-2 = 2-way free),
// wat[a][n] broadcast (wave-uniform), acc in registers.
// NOTE: hoisted form must use the CONJUGATE product:
//   cc.x*Re(w^l) + cc.y*Im(w^l) = wa.x*(cc.x*wb.x + cc.y*wb.y) + wa.y*(cc.y*wb.x - cc.x*wb.y)
// (round-3 bug: used Re(cc*w^l), wrong sign on cc.y terms -> absmax 1.16)
__global__ __launch_bounds__(256) void k_kgen(
    const float* __restrict__ w_re, const float* __restrict__ w_im,
    const float* __restrict__ ccr, const float* __restrict__ cci,
    const float* __restrict__ Dvec,
    f16* __restrict__ Ke, f16* __restrict__ Ko) {
  __shared__ float2 wbt[64][65];   // [n][j]
  __shared__ float2 wat[32][66];   // [a][n]
  __shared__ float2 ccs[64];
  __shared__ float Kf[2048];
  int h = blockIdx.x, tid = threadIdx.x;
  if (tid < 64) {
    int n = tid;
    double wr = (double)w_re[h*64+n], wi = (double)w_im[h*64+n];
    double br = 1.0, bi = 0.0;
    for (int j = 0; j < 64; ++j) {
      wbt[n][j] = make_float2((float)br, (float)bi);
      double t = br*wr - bi*wi; bi = br*wi + bi*wr; br = t;
    }
    double ar = 1.0, ai = 0.0;   // (br,bi) = w^64 now
    for (int a = 0; a < 32; ++a) {
      wat[a][n] = make_float2((float)ar, (float)ai);
      double t = ar*br - ai*bi; ai = ar*bi + ai*br; ar = t;
    }
    ccs[n] = make_float2(ccr[h*64+n], cci[h*64+n]);
  }
  __syncthreads();
  int lane = tid & 63, wv = tid >> 6;
  float acc[8] = {0.f,0.f,0.f,0.f,0.f,0.f,0.f,0.f};
  for (int n = 0; n < 64; ++n) {
    float2 wb = wbt[n][lane];
    float2 cc = ccs[n];
    float tr = fmaf(cc.y, wb.y,  cc.x*wb.x);   // cc.x*wb.x + cc.y*wb.y
    float ti = fmaf(cc.y, wb.x, -cc.x*wb.y);   // cc.y*wb.x - cc.x*wb.y
    #pragma unroll
    for (int li = 0; li < 8; ++li) {
      float2 wa = wat[wv + 4*li][n];
      acc[li] = fmaf(wa.x, tr, acc[li]);
      acc[li] = fmaf(wa.y, ti, acc[li]);
    }
  }
  #pragma unroll
  for (int li = 0; li < 8; ++li)
    Kf[(wv + 4*li)*64 + lane] = acc[li];
  __syncthreads();
  if (tid == 0) Kf[0] += Dvec[h];
  __syncthreads();
  f16* keh = Ke + (size_t)h*KGP;
  f16* koh = Ko + (size_t)h*KGP;
  for (int q = tid; q < KGP; q += 256) {
    float e = (q < 2048) ? Kf[2047 - q] : 0.f;   // KR[q] = K[2047-q]
    float o = (q < 2047) ? Kf[2046 - q] : 0.f;   // KRo[q] = KR[q+1]
    keh[q] = (f16)e; koh[q] = (f16)o;
  }
}

// ---------------- S4 causal conv as Toeplitz MFMA + GELU ----------------
// one block per h; U[16 b][2048 l] fp16 in LDS (XOR-swizzled granules);
// A-frags from L2 (even/odd reversed-kernel copies) via register sliding window.
__device__ __forceinline__ f16x8 ldfrag(const f16* __restrict__ ke,
                                        const f16* __restrict__ ko, int q) {
  const f16* p = (q & 1) ? (ko + (q - 1)) : (ke + q);   // 4B-aligned either way
  union { uint32_t u[4]; f16x8 v; } r;
  const uint32_t* pu = (const uint32_t*)p;
  r.u[0] = pu[0]; r.u[1] = pu[1]; r.u[2] = pu[2]; r.u[3] = pu[3];
  return r.v;
}

__global__ __launch_bounds__(256) void k_conv(
    const f16* __restrict__ u, const f16* __restrict__ Ke, const f16* __restrict__ Ko,
    f16* __restrict__ g) {
  __shared__ __align__(16) f16 Ul[16*2048];   // exactly 64 KB
  int h = blockIdx.x, tid = threadIdx.x;
  {
    int b = tid >> 4, pr = tid & 15;
    const f16* src = u + ((size_t)b*Hch + h)*Lsq;
    f16* dst = &Ul[b*2048];
    #pragma unroll
    for (int c = 0; c < 16; ++c) {
      int gs = c*16 + pr;                       // granule (8 f16)
      *(f16x8*)&dst[(gs ^ b)*8] = *(const f16x8*)(src + gs*8);
    }
  }
  __syncthreads();
  int wv = tid >> 6, lane = tid & 63;
  int m = lane & 15, qd = lane >> 4;            // m: A-row / B-col(b) / D-col
  const f16* keh = Ke + (size_t)h*KGP;
  const f16* koh = Ko + (size_t)h*KGP;
  f16* gb = g + ((size_t)m*Hch + h)*Lsq;        // output batch = m
  const f16* ulb = &Ul[m*2048];
  for (int pass = 0; pass < 4; ++pass) {
    int P = pass*4 + ((wv + pass) & 3);         // balanced panel rotation
    int i0 = P*128;
    int qb0 = 2047 - i0 - m + qd*8;             // frag q: qb0 - 16t + 32s (+e)
    f32x4 acc[8];
    #pragma unroll
    for (int t = 0; t < 8; ++t) acc[t] = (f32x4){0.f,0.f,0.f,0.f};
    f16x8 W[8];
    #pragma unroll
    for (int t = 0; t < 8; ++t) W[t] = ldfrag(keh, koh, qb0 - 16*t);
    int steps = 4*(P+1);
    for (int s4i = 0; s4i < steps; s4i += 4) {
      #pragma unroll
      for (int ph = 0; ph < 4; ++ph) {
        int s = s4i + ph;
        f16x8 bf = *(const f16x8*)&ulb[((4*s + qd) ^ m)*8];
        // prefetch next step's two fresh frags (padded region keeps OOB safe)
        f16x8 nf0 = ldfrag(keh, koh, qb0 + 32*(s+1));
        f16x8 nf1 = ldfrag(keh, koh, qb0 - 16 + 32*(s+1));
        #pragma unroll
        for (int t = 0; t < 8; ++t)
          acc[t] = __builtin_amdgcn_mfma_f32_16x16x32_f16(W[(t - 2*ph) & 7], bf, acc[t], 0, 0, 0);
        W[(6 - 2*ph) & 7] = nf0;   // tile 0 of step s+1
        W[(7 - 2*ph) & 7] = nf1;   // tile 1 of step s+1
      }
    }
    #pragma unroll
    for (int t = 0; t < 8; ++t) {
      f16x4 o;
      #pragma unroll
      for (int r = 0; r < 4; ++r) o[r] = (f16)gelu_tanh(acc[t][r]);
      *(f16x4*)&gb[i0 + 16*t + qd*4] = o;
    }
  }
}

// ---------------- MFMA fp16 GEMM, BM=BN=128, BK=32, 4 waves ----------------
// Bs layout: [n 0..127][k-pair 0..15], pitch 20 words -> B-frag = 1x ds_read_b128
// MODE 0: out fp16 = W@act + bias              (in-projection)
// MODE 1: out fp16 = (Wa@act+ba)*sigmoid(Wb@act+bb)   (oW + GLU, Wb = rows 512..1023)
// MODE 2: out fp32: rows<256 -> (x + v)/sqrt2 ; rows>=256 -> skip  (out-projection)
template<int KD, int MODE>
__global__ __launch_bounds__(256) void k_gemm(
    const f16* __restrict__ W, const f16* __restrict__ Bact,
    const float* __restrict__ bias, const float* __restrict__ xres,
    float* __restrict__ outF, f16* __restrict__ outH) {
  constexpr int NT = (MODE == 1) ? 2 : 1;
  __shared__ __align__(16) f16 As[NT][128][40];
  __shared__ __align__(16) uint32_t Bs[128*20];
  int tid = threadIdx.x;
  int wv = tid >> 6, lane = tid & 63;
  int nt = blockIdx.x;            // 0..255
  int mt = blockIdx.y;            // 0..3
  int bb = nt >> 4;
  int l0 = (nt & 15)*128;
  int m0 = mt*128;
  int wm = (wv & 1)*64, wn = (wv >> 1)*64;
  int qd = lane >> 4, ln16 = lane & 15;

  f32x4 acc[NT][4][4];
  #pragma unroll
  for (int t = 0; t < NT; ++t)
    for (int i = 0; i < 4; ++i)
      for (int j = 0; j < 4; ++j)
        acc[t][i][j] = (f32x4){0.f,0.f,0.f,0.f};

  const f16* Bbase = Bact + (size_t)bb*KD*Lsq + l0;
  int kp = tid & 15, nch = tid >> 4;

  for (int kk = 0; kk < KD; kk += 32) {
    #pragma unroll
    for (int c = 0; c < 2*NT; ++c) {
      int c2 = tid + 256*(c & 1);
      int row = c2 >> 2;
      int kc = (c2 & 3)*8;
      int tsel = c >> 1;
      const f16* src = W + (size_t)(m0 + row + tsel*512)*KD + kk + kc;
      *(f16x8*)&As[tsel][row][kc] = *(const f16x8*)src;
    }
    {
      const f16* b0 = Bbase + (size_t)(kk + 2*kp)*Lsq + nch*8;
      f16x8 r0 = *(const f16x8*)b0;
      f16x8 r1 = *(const f16x8*)(b0 + Lsq);
      #pragma unroll
      for (int e = 0; e < 8; ++e) {
        union { f16 h2[2]; uint32_t w; } pk;
        pk.h2[0] = r0[e]; pk.h2[1] = r1[e];
        Bs[(nch*8 + e)*20 + kp] = pk.w;
      }
    }
    __syncthreads();
    f16x8 afr[NT][4];
    #pragma unroll
    for (int i = 0; i < 4; ++i)
      for (int t = 0; t < NT; ++t)
        afr[t][i] = *(const f16x8*)&As[t][wm + i*16 + ln16][qd*8];
    f16x8 bfr[4];
    #pragma unroll
    for (int j = 0; j < 4; ++j) {
      int n = wn + j*16 + ln16;
      bfr[j] = *(const f16x8*)&Bs[n*20 + qd*4];
    }
    #pragma unroll
    for (int j = 0; j < 4; ++j)
      for (int i = 0; i < 4; ++i)
        for (int t = 0; t < NT; ++t)
          acc[t][i][j] = __builtin_amdgcn_mfma_f32_16x16x32_f16(afr[t][i], bfr[j], acc[t][i][j], 0, 0, 0);
    __syncthreads();
  }

  #pragma unroll
  for (int i = 0; i < 4; ++i)
    for (int j = 0; j < 4; ++j)
      for (int r = 0; r < 4; ++r) {
        int ml = wm + i*16 + qd*4 + r;
        int nl = wn + j*16 + ln16;
        int mg = m0 + ml;
        int l  = l0 + nl;
        if (MODE == 0) {
          outH[((size_t)bb*Hch + mg)*Lsq + l] = (f16)(acc[0][i][j][r] + bias[mg]);
        } else if (MODE == 1) {
          float va = acc[0][i][j][r] + bias[mg];
          float vb = acc[1][i][j][r] + bias[512 + mg];
          outH[((size_t)bb*Hch + mg)*Lsq + l] = (f16)(va * sigmoidf_(vb));
        } else {
          float v = acc[0][i][j][r] + bias[mg];
          if (mg < Cch) {
            size_t idx = ((size_t)bb*Cch + mg)*Lsq + l;
            outF[idx] = (v + xres[idx]) * 0.7071067811865476f;
          } else {
            size_t idx = ((size_t)bb*Cch + (mg - Cch))*Lsq + l;
            outF[(size_t)Bsz*Cch*Lsq + idx] = v;
          }
        }
      }
}

// ---------------- LayerNorm over channels (fp16 in) ----------------
// MODE 0: fp16 out (LN only).  MODE 1: fused gate: sigmoid(yn[c])*tanh(yn[c+256]), fp16 out
template<int MODE>
__global__ __launch_bounds__(256) void k_ln(const f16* __restrict__ v,
                                            const float* __restrict__ gam, const float* __restrict__ bet,
                                            float* __restrict__ outF, f16* __restrict__ outH) {
  __shared__ float red[2][4][64];
  int b = blockIdx.x >> 5;
  int l = (blockIdx.x & 31)*64 + (threadIdx.x & 63);
  int wv = threadIdx.x >> 6, lane = threadIdx.x & 63;
  const f16* base = v + (size_t)b*Hch*Lsq + l;
  float s = 0.f, s2 = 0.f;
  for (int h = wv*128; h < wv*128 + 128; ++h) {
    float xv = (float)base[(size_t)h*Lsq];
    s += xv; s2 += xv*xv;
  }
  red[0][wv][lane] = s; red[1][wv][lane] = s2;
  __syncthreads();
  s  = red[0][0][lane] + red[0][1][lane] + red[0][2][lane] + red[0][3][lane];
  s2 = red[1][0][lane] + red[1][1][lane] + red[1][2][lane] + red[1][3][lane];
  float mu = s*(1.0f/Hch);
  float var = s2*(1.0f/Hch) - mu*mu;
  float rs = rsqrtf(var + 1e-5f);
  if (MODE == 0) {
    f16* ob = outH + (size_t)b*Hch*Lsq + l;
    for (int h = wv*128; h < wv*128 + 128; ++h)
      ob[(size_t)h*Lsq] = (f16)(((float)base[(size_t)h*Lsq] - mu)*rs*gam[h] + bet[h]);
  } else {
    f16* ob = outH + (size_t)b*Cch*Lsq + l;
    for (int c = wv*64; c < wv*64 + 64; ++c) {
      float xg = ((float)base[(size_t)c*Lsq] - mu)*rs*gam[c] + bet[c];
      float xf = ((float)base[(size_t)(c+Cch)*Lsq] - mu)*rs*gam[c+Cch] + bet[c+Cch];
      float xfc = fminf(fmaxf(xf, -15.f), 15.f);
      float e = __expf(2.f*xfc);
      ob[(size_t)c*Lsq] = (f16)(sigmoidf_(xg) * ((e-1.f)/(e+1.f)));
    }
  }
}

// ---------------- launch ----------------
extern "C" void kernel_launch(void* const* d_in, const int* in_sizes, int n_in,
                              void* d_out, int out_size, void* d_ws, size_t ws_size,
                              hipStream_t stream) {
  const float* x    = (const float*)d_in[0];
  const float* emb  = (const float*)d_in[1];
  const float* dpW  = (const float*)d_in[2];
  const float* dpb  = (const float*)d_in[3];
  const float* inW  = (const float*)d_in[4];
  const float* inb  = (const float*)d_in[5];
  const float* outW = (const float*)d_in[6];
  const float* outb = (const float*)d_in[7];
  const float* ln1g = (const float*)d_in[8];
  const float* ln1b = (const float*)d_in[9];
  const float* ln2g = (const float*)d_in[10];
  const float* ln2b = (const float*)d_in[11];
  const float* s4[2][8];
  for (int ly = 0; ly < 2; ++ly)
    for (int k = 0; k < 8; ++k) s4[ly][k] = (const float*)d_in[12 + ly*8 + k];
  // s4[ly]: 0 log_dt, 1 A_re, 2 A_im, 3 C_re, 4 C_im, 5 D, 6 oW, 7 ob

  char* p = (char*)d_ws;
  auto alloc = [&](size_t bytes) { char* r = p; p += (bytes + 255) & ~(size_t)255; return r; };
  f16* inW16  = (f16*)alloc((size_t)Hch*Cch*2);
  f16* oW16_0 = (f16*)alloc((size_t)2*Hch*Hch*2);
  f16* oW16_1 = (f16*)alloc((size_t)2*Hch*Hch*2);
  f16* outW16 = (f16*)alloc((size_t)2*Cch*Cch*2);
  float* dbuf = (float*)alloc((size_t)Bsz*Cch*4);
  float* prm[2][4];
  for (int ly = 0; ly < 2; ++ly)
    for (int k = 0; k < 4; ++k) prm[ly][k] = (float*)alloc((size_t)Hch*Nst*4);
  f16* kge[2], *kgo[2];
  for (int ly = 0; ly < 2; ++ly) {
    kge[ly] = (f16*)alloc((size_t)Hch*KGP*2);
    kgo[ly] = (f16*)alloc((size_t)Hch*KGP*2);
  }
  f16*  xd   = (f16*)alloc((size_t)Bsz*Cch*Lsq*2);
  f16*  u16g = (f16*)alloc((size_t)Bsz*Hch*Lsq*2);
  f16*  gbuf = (f16*)alloc((size_t)Bsz*Hch*Lsq*2);
  f16*  glu  = (f16*)alloc((size_t)Bsz*Hch*Lsq*2);
  f16*  oW16[2] = {oW16_0, oW16_1};

  // prep
  k_emb<<<Bsz, Cch, 0, stream>>>(emb, dpW, dpb, dbuf);
  k_f2h<<<(Hch*Cch+255)/256, 256, 0, stream>>>(inW, inW16, Hch*Cch);
  k_f2h<<<(2*Hch*Hch+255)/256, 256, 0, stream>>>(s4[0][6], oW16_0, 2*Hch*Hch);
  k_f2h<<<(2*Hch*Hch+255)/256, 256, 0, stream>>>(s4[1][6], oW16_1, 2*Hch*Hch);
  k_f2h<<<(2*Cch*Cch+255)/256, 256, 0, stream>>>(outW, outW16, 2*Cch*Cch);
  for (int ly = 0; ly < 2; ++ly) {
    k_s4prep<<<(Hch*Nst+255)/256, 256, 0, stream>>>(s4[ly][0], s4[ly][1], s4[ly][2],
        s4[ly][3], s4[ly][4], prm[ly][0], prm[ly][1], prm[ly][2], prm[ly][3]);
    k_kgen<<<Hch, 256, 0, stream>>>(prm[ly][0], prm[ly][1], prm[ly][2], prm[ly][3],
        s4[ly][5], kge[ly], kgo[ly]);
  }
  k_addemb<<<(Bsz*Cch*Lsq/4)/256, 256, 0, stream>>>(x, dbuf, xd);

  dim3 gg(256, 4), bl(256);
  // in-projection (fp16 out)
  k_gemm<Cch, 0><<<gg, bl, 0, stream>>>(inW16, xd, inb, nullptr, nullptr, u16g);
  // S4 layer 1
  k_conv<<<Hch, 256, 0, stream>>>(u16g, kge[0], kgo[0], gbuf);
  k_gemm<Hch, 1><<<gg, bl, 0, stream>>>(oW16[0], gbuf, s4[0][7], nullptr, nullptr, glu);
  k_ln<0><<<Bsz*32, 256, 0, stream>>>(glu, ln1g, ln1b, nullptr, u16g);
  // S4 layer 2
  k_conv<<<Hch, 256, 0, stream>>>(u16g, kge[1], kgo[1], gbuf);
  k_gemm<Hch, 1><<<gg, bl, 0, stream>>>(oW16[1], gbuf, s4[1][7], nullptr, nullptr, glu);
  k_ln<1><<<Bsz*32, 256, 0, stream>>>(glu, ln2g, ln2b, nullptr, xd);
  // out-projection (+ residual/skip split)
  k_gemm<Cch, 2><<<gg, bl, 0, stream>>>(outW16, xd, outb, x, (float*)d_out, nullptr);
}

// Round 5
// 598.364 us; speedup vs baseline: 1.9396x; 1.0193x over previous
//
#include <hip/hip_runtime.h>
#include <math.h>

#define Bsz 16
#define Cch 256
#define Lsq 2048
#define Emb 512
#define Nst 64
#define Hch 512   // 2C
#define KGP 2240  // padded reversed-kernel pitch per h

typedef _Float16 f16;
typedef _Float16 f16x8 __attribute__((ext_vector_type(8)));
typedef _Float16 f16x4 __attribute__((ext_vector_type(4)));
typedef float f32x4 __attribute__((ext_vector_type(4)));
typedef uint32_t u32x4 __attribute__((ext_vector_type(4)));

__device__ __forceinline__ float sigmoidf_(float x) { return 1.0f/(1.0f + __expf(-x)); }
__device__ __forceinline__ float gelu_tanh(float y) {
  float z = 0.7978845608028654f*(y + 0.044715f*y*y*y);
  return 0.5f*y*(1.0f + tanhf(z));
}

// ---------------- small prep kernels ----------------

__global__ void k_emb(const float* __restrict__ emb, const float* __restrict__ dpW,
                      const float* __restrict__ dpb, float* __restrict__ d) {
  int b = blockIdx.x, c = threadIdx.x;
  const float* e = emb + b*Emb;
  const float* w = dpW + c*Emb;
  float s = dpb[c];
  for (int k = 0; k < Emb; ++k) s += e[k]*w[k];
  d[b*Cch + c] = s;
}

__global__ void k_f2h(const float* __restrict__ src, f16* __restrict__ dst, int n) {
  int i = blockIdx.x*256 + threadIdx.x;
  if (i < n) dst[i] = (f16)src[i];
}

__global__ void k_addemb(const float* __restrict__ x, const float* __restrict__ d,
                         f16* __restrict__ xd) {
  int i = blockIdx.x*256 + threadIdx.x;          // over B*C*L/4
  const float4* x4 = (const float4*)x;
  float4 v = x4[i];
  int bc = (i*4)/Lsq;
  float dd = d[bc];
  f16x4 o;
  o[0] = (f16)(v.x+dd); o[1] = (f16)(v.y+dd); o[2] = (f16)(v.z+dd); o[3] = (f16)(v.w+dd);
  ((f16x4*)xd)[i] = o;
}

// Per (h,n): w = exp(dt*A), cc = 2*Ct (re / -im) with Ct = C*(w-1)/A
__global__ void k_s4prep(const float* __restrict__ log_dt,
                         const float* __restrict__ A_re, const float* __restrict__ A_im,
                         const float* __restrict__ C_re, const float* __restrict__ C_im,
                         float* __restrict__ w_re, float* __restrict__ w_im,
                         float* __restrict__ ccr, float* __restrict__ cci) {
  int i = blockIdx.x*256 + threadIdx.x;
  if (i >= Hch*Nst) return;
  int h = i >> 6;
  float dt = expf(log_dt[h]);
  float Ar = A_re[i], Ai = A_im[i];
  float er = expf(dt*Ar);
  float wr = er*cosf(dt*Ai), wi = er*sinf(dt*Ai);
  float mag = Ar*Ar + Ai*Ai;
  float nr = wr - 1.0f, ni = wi;
  float qr = (nr*Ar + ni*Ai)/mag, qi = (ni*Ar - nr*Ai)/mag;
  float cr = C_re[i], ci = C_im[i];
  float tr = cr*qr - ci*qi, ti = cr*qi + ci*qr;
  w_re[i] = wr; w_im[i] = wi; ccr[i] = 2.0f*tr; cci[i] = -2.0f*ti;
}

// ---------------- kernel generation: K[h,l] = sum_n ccr*Re(w^l)+cci*Im(w^l), K[0]+=D ----
// transposed tables: wbt[n][j] (lane=j reads stride-2 = 2-way free),
// wat[a][n] broadcast (wave-uniform), acc in registers.
// Hoisted form uses the CONJUGATE product:
//   cc.x*Re(w^l) + cc.y*Im(w^l) = wa.x*(cc.x*wb.x + cc.y*wb.y) + wa.y*(cc.y*wb.x - cc.x*wb.y)
__global__ __launch_bounds__(256) void k_kgen(
    const float* __restrict__ w_re, const float* __restrict__ w_im,
    const float* __restrict__ ccr, const float* __restrict__ cci,
    const float* __restrict__ Dvec,
    f16* __restrict__ Ke, f16* __restrict__ Ko) {
  __shared__ float2 wbt[64][65];   // [n][j]
  __shared__ float2 wat[32][66];   // [a][n]
  __shared__ float2 ccs[64];
  __shared__ float Kf[2048];
  int h = blockIdx.x, tid = threadIdx.x;
  if (tid < 64) {
    int n = tid;
    double wr = (double)w_re[h*64+n], wi = (double)w_im[h*64+n];
    double br = 1.0, bi = 0.0;
    for (int j = 0; j < 64; ++j) {
      wbt[n][j] = make_float2((float)br, (float)bi);
      double t = br*wr - bi*wi; bi = br*wi + bi*wr; br = t;
    }
    double ar = 1.0, ai = 0.0;   // (br,bi) = w^64 now
    for (int a = 0; a < 32; ++a) {
      wat[a][n] = make_float2((float)ar, (float)ai);
      double t = ar*br - ai*bi; ai = ar*bi + ai*br; ar = t;
    }
    ccs[n] = make_float2(ccr[h*64+n], cci[h*64+n]);
  }
  __syncthreads();
  int lane = tid & 63, wv = tid >> 6;
  float acc[8] = {0.f,0.f,0.f,0.f,0.f,0.f,0.f,0.f};
  for (int n = 0; n < 64; ++n) {
    float2 wb = wbt[n][lane];
    float2 cc = ccs[n];
    float tr = fmaf(cc.y, wb.y,  cc.x*wb.x);   // cc.x*wb.x + cc.y*wb.y
    float ti = fmaf(cc.y, wb.x, -cc.x*wb.y);   // cc.y*wb.x - cc.x*wb.y
    #pragma unroll
    for (int li = 0; li < 8; ++li) {
      float2 wa = wat[wv + 4*li][n];
      acc[li] = fmaf(wa.x, tr, acc[li]);
      acc[li] = fmaf(wa.y, ti, acc[li]);
    }
  }
  #pragma unroll
  for (int li = 0; li < 8; ++li)
    Kf[(wv + 4*li)*64 + lane] = acc[li];
  __syncthreads();
  if (tid == 0) Kf[0] += Dvec[h];
  __syncthreads();
  f16* keh = Ke + (size_t)h*KGP;
  f16* koh = Ko + (size_t)h*KGP;
  for (int q = tid; q < KGP; q += 256) {
    float e = (q < 2048) ? Kf[2047 - q] : 0.f;   // KR[q] = K[2047-q]
    float o = (q < 2047) ? Kf[2046 - q] : 0.f;   // KRo[q] = KR[q+1]
    keh[q] = (f16)e; koh[q] = (f16)o;
  }
}

// ---------------- S4 causal conv as Toeplitz MFMA + GELU ----------------
// one block per h; U[16 b][2048 l] fp16 in LDS (XOR-swizzled granules);
// A-frags from L2 (even/odd reversed-kernel copies) via register sliding window.
__device__ __forceinline__ f16x8 ldfrag(const f16* __restrict__ ke,
                                        const f16* __restrict__ ko, int q) {
  const f16* p = (q & 1) ? (ko + (q - 1)) : (ke + q);   // 4B-aligned either way
  union { uint32_t u[4]; f16x8 v; } r;
  const uint32_t* pu = (const uint32_t*)p;
  r.u[0] = pu[0]; r.u[1] = pu[1]; r.u[2] = pu[2]; r.u[3] = pu[3];
  return r.v;
}

__global__ __launch_bounds__(256) void k_conv(
    const f16* __restrict__ u, const f16* __restrict__ Ke, const f16* __restrict__ Ko,
    f16* __restrict__ g) {
  __shared__ __align__(16) f16 Ul[16*2048];   // exactly 64 KB
  int h = blockIdx.x, tid = threadIdx.x;
  {
    int b = tid >> 4, pr = tid & 15;
    const f16* src = u + ((size_t)b*Hch + h)*Lsq;
    f16* dst = &Ul[b*2048];
    #pragma unroll
    for (int c = 0; c < 16; ++c) {
      int gs = c*16 + pr;                       // granule (8 f16)
      *(f16x8*)&dst[(gs ^ b)*8] = *(const f16x8*)(src + gs*8);
    }
  }
  __syncthreads();
  int wv = tid >> 6, lane = tid & 63;
  int m = lane & 15, qd = lane >> 4;            // m: A-row / B-col(b) / D-col
  const f16* keh = Ke + (size_t)h*KGP;
  const f16* koh = Ko + (size_t)h*KGP;
  f16* gb = g + ((size_t)m*Hch + h)*Lsq;        // output batch = m
  const f16* ulb = &Ul[m*2048];
  for (int pass = 0; pass < 4; ++pass) {
    int P = pass*4 + ((wv + pass) & 3);         // balanced panel rotation
    int i0 = P*128;
    int qb0 = 2047 - i0 - m + qd*8;             // frag q: qb0 - 16t + 32s (+e)
    f32x4 acc[8];
    #pragma unroll
    for (int t = 0; t < 8; ++t) acc[t] = (f32x4){0.f,0.f,0.f,0.f};
    f16x8 W[8];
    #pragma unroll
    for (int t = 0; t < 8; ++t) W[t] = ldfrag(keh, koh, qb0 - 16*t);
    int steps = 4*(P+1);
    for (int s4i = 0; s4i < steps; s4i += 4) {
      #pragma unroll
      for (int ph = 0; ph < 4; ++ph) {
        int s = s4i + ph;
        f16x8 bf = *(const f16x8*)&ulb[((4*s + qd) ^ m)*8];
        // prefetch next step's two fresh frags (padded region keeps OOB safe)
        f16x8 nf0 = ldfrag(keh, koh, qb0 + 32*(s+1));
        f16x8 nf1 = ldfrag(keh, koh, qb0 - 16 + 32*(s+1));
        #pragma unroll
        for (int t = 0; t < 8; ++t)
          acc[t] = __builtin_amdgcn_mfma_f32_16x16x32_f16(W[(t - 2*ph) & 7], bf, acc[t], 0, 0, 0);
        W[(6 - 2*ph) & 7] = nf0;   // tile 0 of step s+1
        W[(7 - 2*ph) & 7] = nf1;   // tile 1 of step s+1
      }
    }
    #pragma unroll
    for (int t = 0; t < 8; ++t) {
      f16x4 o;
      #pragma unroll
      for (int r = 0; r < 4; ++r) o[r] = (f16)gelu_tanh(acc[t][r]);
      *(f16x4*)&gb[i0 + 16*t + qd*4] = o;
    }
  }
}

// ---------------- MFMA fp16 GEMM, BM=BN=128, BK=32, 4 waves ----------------
// B staging: COALESCED loads (q16 = k-pair = tid>>4, nch = col-chunk = tid&15:
// lanes 0..15 read 256B contiguous). Bs layout pair-major [kp][n], pitch 132
// words: writes = 2x ds_write_b128 (conflict-free), frag reads = 4x b32
// (2-way = free: bank = 16*qd + ln16 + const).
// MODE 0: out fp16 = W@act + bias              (in-projection)
// MODE 1: out fp16 = (Wa@act+ba)*sigmoid(Wb@act+bb)   (oW + GLU, Wb = rows 512..1023)
// MODE 2: out fp32: rows<256 -> (x + v)/sqrt2 ; rows>=256 -> skip  (out-projection)
template<int KD, int MODE>
__global__ __launch_bounds__(256) void k_gemm(
    const f16* __restrict__ W, const f16* __restrict__ Bact,
    const float* __restrict__ bias, const float* __restrict__ xres,
    float* __restrict__ outF, f16* __restrict__ outH) {
  constexpr int NT = (MODE == 1) ? 2 : 1;
  __shared__ __align__(16) f16 As[NT][128][40];
  __shared__ __align__(16) uint32_t Bs[16*132];   // [kp][n], 8448 B
  int tid = threadIdx.x;
  int wv = tid >> 6, lane = tid & 63;
  int nt = blockIdx.x;            // 0..255
  int mt = blockIdx.y;            // 0..3
  int bb = nt >> 4;
  int l0 = (nt & 15)*128;
  int m0 = mt*128;
  int wm = (wv & 1)*64, wn = (wv >> 1)*64;
  int qd = lane >> 4, ln16 = lane & 15;

  f32x4 acc[NT][4][4];
  #pragma unroll
  for (int t = 0; t < NT; ++t)
    for (int i = 0; i < 4; ++i)
      for (int j = 0; j < 4; ++j)
        acc[t][i][j] = (f32x4){0.f,0.f,0.f,0.f};

  const f16* Bbase = Bact + (size_t)bb*KD*Lsq + l0;
  int q16 = tid >> 4, nch = tid & 15;

  for (int kk = 0; kk < KD; kk += 32) {
    // stage A tile(s): rows m0..m0+127 (+512 for second tile), k kk..kk+31
    #pragma unroll
    for (int c = 0; c < 2*NT; ++c) {
      int c2 = tid + 256*(c & 1);
      int row = c2 >> 2;
      int kc = (c2 & 3)*8;
      int tsel = c >> 1;
      const f16* src = W + (size_t)(m0 + row + tsel*512)*KD + kk + kc;
      *(f16x8*)&As[tsel][row][kc] = *(const f16x8*)src;
    }
    // stage B: coalesced rows (kk+2q16, kk+2q16+1), cols nch*8..+7; pack pairs
    {
      const f16* b0 = Bbase + (size_t)(kk + 2*q16)*Lsq + nch*8;
      f16x8 r0 = *(const f16x8*)b0;
      f16x8 r1 = *(const f16x8*)(b0 + Lsq);
      union { uint32_t w[8]; u32x4 v[2]; } pk;
      #pragma unroll
      for (int e = 0; e < 8; ++e) {
        union { f16 h2[2]; uint32_t u; } t2;
        t2.h2[0] = r0[e]; t2.h2[1] = r1[e];
        pk.w[e] = t2.u;
      }
      *(u32x4*)&Bs[q16*132 + nch*8]     = pk.v[0];
      *(u32x4*)&Bs[q16*132 + nch*8 + 4] = pk.v[1];
    }
    __syncthreads();
    f16x8 afr[NT][4];
    #pragma unroll
    for (int i = 0; i < 4; ++i)
      for (int t = 0; t < NT; ++t)
        afr[t][i] = *(const f16x8*)&As[t][wm + i*16 + ln16][qd*8];
    f16x8 bfr[4];
    #pragma unroll
    for (int j = 0; j < 4; ++j) {
      int n = wn + j*16 + ln16;
      union { uint32_t w2[4]; f16x8 v; } bu;
      #pragma unroll
      for (int r2 = 0; r2 < 4; ++r2) bu.w2[r2] = Bs[(qd*4 + r2)*132 + n];
      bfr[j] = bu.v;
    }
    #pragma unroll
    for (int j = 0; j < 4; ++j)
      for (int i = 0; i < 4; ++i)
        for (int t = 0; t < NT; ++t)
          acc[t][i][j] = __builtin_amdgcn_mfma_f32_16x16x32_f16(afr[t][i], bfr[j], acc[t][i][j], 0, 0, 0);
    __syncthreads();
  }

  #pragma unroll
  for (int i = 0; i < 4; ++i)
    for (int j = 0; j < 4; ++j)
      for (int r = 0; r < 4; ++r) {
        int ml = wm + i*16 + qd*4 + r;
        int nl = wn + j*16 + ln16;
        int mg = m0 + ml;
        int l  = l0 + nl;
        if (MODE == 0) {
          outH[((size_t)bb*Hch + mg)*Lsq + l] = (f16)(acc[0][i][j][r] + bias[mg]);
        } else if (MODE == 1) {
          float va = acc[0][i][j][r] + bias[mg];
          float vb = acc[1][i][j][r] + bias[512 + mg];
          outH[((size_t)bb*Hch + mg)*Lsq + l] = (f16)(va * sigmoidf_(vb));
        } else {
          float v = acc[0][i][j][r] + bias[mg];
          if (mg < Cch) {
            size_t idx = ((size_t)bb*Cch + mg)*Lsq + l;
            outF[idx] = (v + xres[idx]) * 0.7071067811865476f;
          } else {
            size_t idx = ((size_t)bb*Cch + (mg - Cch))*Lsq + l;
            outF[(size_t)Bsz*Cch*Lsq + idx] = v;
          }
        }
      }
}

// ---------------- LayerNorm over channels (fp16 in) ----------------
// MODE 0: fp16 out (LN only).  MODE 1: fused gate: sigmoid(yn[c])*tanh(yn[c+256]), fp16 out
template<int MODE>
__global__ __launch_bounds__(256) void k_ln(const f16* __restrict__ v,
                                            const float* __restrict__ gam, const float* __restrict__ bet,
                                            float* __restrict__ outF, f16* __restrict__ outH) {
  __shared__ float red[2][4][64];
  int b = blockIdx.x >> 5;
  int l = (blockIdx.x & 31)*64 + (threadIdx.x & 63);
  int wv = threadIdx.x >> 6, lane = threadIdx.x & 63;
  const f16* base = v + (size_t)b*Hch*Lsq + l;
  float s = 0.f, s2 = 0.f;
  for (int h = wv*128; h < wv*128 + 128; ++h) {
    float xv = (float)base[(size_t)h*Lsq];
    s += xv; s2 += xv*xv;
  }
  red[0][wv][lane] = s; red[1][wv][lane] = s2;
  __syncthreads();
  s  = red[0][0][lane] + red[0][1][lane] + red[0][2][lane] + red[0][3][lane];
  s2 = red[1][0][lane] + red[1][1][lane] + red[1][2][lane] + red[1][3][lane];
  float mu = s*(1.0f/Hch);
  float var = s2*(1.0f/Hch) - mu*mu;
  float rs = rsqrtf(var + 1e-5f);
  if (MODE == 0) {
    f16* ob = outH + (size_t)b*Hch*Lsq + l;
    for (int h = wv*128; h < wv*128 + 128; ++h)
      ob[(size_t)h*Lsq] = (f16)(((float)base[(size_t)h*Lsq] - mu)*rs*gam[h] + bet[h]);
  } else {
    f16* ob = outH + (size_t)b*Cch*Lsq + l;
    for (int c = wv*64; c < wv*64 + 64; ++c) {
      float xg = ((float)base[(size_t)c*Lsq] - mu)*rs*gam[c] + bet[c];
      float xf = ((float)base[(size_t)(c+Cch)*Lsq] - mu)*rs*gam[c+Cch] + bet[c+Cch];
      float xfc = fminf(fmaxf(xf, -15.f), 15.f);
      float e = __expf(2.f*xfc);
      ob[(size_t)c*Lsq] = (f16)(sigmoidf_(xg) * ((e-1.f)/(e+1.f)));
    }
  }
}

// ---------------- launch ----------------
extern "C" void kernel_launch(void* const* d_in, const int* in_sizes, int n_in,
                              void* d_out, int out_size, void* d_ws, size_t ws_size,
                              hipStream_t stream) {
  const float* x    = (const float*)d_in[0];
  const float* emb  = (const float*)d_in[1];
  const float* dpW  = (const float*)d_in[2];
  const float* dpb  = (const float*)d_in[3];
  const float* inW  = (const float*)d_in[4];
  const float* inb  = (const float*)d_in[5];
  const float* outW = (const float*)d_in[6];
  const float* outb = (const float*)d_in[7];
  const float* ln1g = (const float*)d_in[8];
  const float* ln1b = (const float*)d_in[9];
  const float* ln2g = (const float*)d_in[10];
  const float* ln2b = (const float*)d_in[11];
  const float* s4[2][8];
  for (int ly = 0; ly < 2; ++ly)
    for (int k = 0; k < 8; ++k) s4[ly][k] = (const float*)d_in[12 + ly*8 + k];
  // s4[ly]: 0 log_dt, 1 A_re, 2 A_im, 3 C_re, 4 C_im, 5 D, 6 oW, 7 ob

  char* p = (char*)d_ws;
  auto alloc = [&](size_t bytes) { char* r = p; p += (bytes + 255) & ~(size_t)255; return r; };
  f16* inW16  = (f16*)alloc((size_t)Hch*Cch*2);
  f16* oW16_0 = (f16*)alloc((size_t)2*Hch*Hch*2);
  f16* oW16_1 = (f16*)alloc((size_t)2*Hch*Hch*2);
  f16* outW16 = (f16*)alloc((size_t)2*Cch*Cch*2);
  float* dbuf = (float*)alloc((size_t)Bsz*Cch*4);
  float* prm[2][4];
  for (int ly = 0; ly < 2; ++ly)
    for (int k = 0; k < 4; ++k) prm[ly][k] = (float*)alloc((size_t)Hch*Nst*4);
  f16* kge[2], *kgo[2];
  for (int ly = 0; ly < 2; ++ly) {
    kge[ly] = (f16*)alloc((size_t)Hch*KGP*2);
    kgo[ly] = (f16*)alloc((size_t)Hch*KGP*2);
  }
  f16*  xd   = (f16*)alloc((size_t)Bsz*Cch*Lsq*2);
  f16*  u16g = (f16*)alloc((size_t)Bsz*Hch*Lsq*2);
  f16*  gbuf = (f16*)alloc((size_t)Bsz*Hch*Lsq*2);
  f16*  glu  = (f16*)alloc((size_t)Bsz*Hch*Lsq*2);
  f16*  oW16[2] = {oW16_0, oW16_1};

  // prep
  k_emb<<<Bsz, Cch, 0, stream>>>(emb, dpW, dpb, dbuf);
  k_f2h<<<(Hch*Cch+255)/256, 256, 0, stream>>>(inW, inW16, Hch*Cch);
  k_f2h<<<(2*Hch*Hch+255)/256, 256, 0, stream>>>(s4[0][6], oW16_0, 2*Hch*Hch);
  k_f2h<<<(2*Hch*Hch+255)/256, 256, 0, stream>>>(s4[1][6], oW16_1, 2*Hch*Hch);
  k_f2h<<<(2*Cch*Cch+255)/256, 256, 0, stream>>>(outW, outW16, 2*Cch*Cch);
  for (int ly = 0; ly < 2; ++ly) {
    k_s4prep<<<(Hch*Nst+255)/256, 256, 0, stream>>>(s4[ly][0], s4[ly][1], s4[ly][2],
        s4[ly][3], s4[ly][4], prm[ly][0], prm[ly][1], prm[ly][2], prm[ly][3]);
    k_kgen<<<Hch, 256, 0, stream>>>(prm[ly][0], prm[ly][1], prm[ly][2], prm[ly][3],
        s4[ly][5], kge[ly], kgo[ly]);
  }
  k_addemb<<<(Bsz*Cch*Lsq/4)/256, 256, 0, stream>>>(x, dbuf, xd);

  dim3 gg(256, 4), bl(256);
  // in-projection (fp16 out)
  k_gemm<Cch, 0><<<gg, bl, 0, stream>>>(inW16, xd, inb, nullptr, nullptr, u16g);
  // S4 layer 1
  k_conv<<<Hch, 256, 0, stream>>>(u16g, kge[0], kgo[0], gbuf);
  k_gemm<Hch, 1><<<gg, bl, 0, stream>>>(oW16[0], gbuf, s4[0][7], nullptr, nullptr, glu);
  k_ln<0><<<Bsz*32, 256, 0, stream>>>(glu, ln1g, ln1b, nullptr, u16g);
  // S4 layer 2
  k_conv<<<Hch, 256, 0, stream>>>(u16g, kge[1], kgo[1], gbuf);
  k_gemm<Hch, 1><<<gg, bl, 0, stream>>>(oW16[1], gbuf, s4[1][7], nullptr, nullptr, glu);
  k_ln<1><<<Bsz*32, 256, 0, stream>>>(glu, ln2g, ln2b, nullptr, xd);
  // out-projection (+ residual/skip split)
  k_gemm<Cch, 2><<<gg, bl, 0, stream>>>(outW16, xd, outb, x, (float*)d_out, nullptr);
}